// Round 6
// baseline (1359.480 us; speedup 1.0000x reference)
//
#include <hip/hip_runtime.h>
#include <cstdint>
#include <cstddef>

#define B_ 4
#define N_ 4096
#define D_ 1024
#define CAND 16
#define M_ (B_*N_)
#define MD_ ((size_t)M_ * D_)
#define DD_ ((size_t)D_ * D_)

typedef __attribute__((ext_vector_type(8))) short short8;
typedef __attribute__((ext_vector_type(4))) float floatx4;

// ---------------------------------------------------------------------------
// Static device-global scratch. Every buffer fully overwritten before first
// read on every call. X planes and W planes are contiguous 3-plane arrays so
// the K-extended GEMM can select a plane by arithmetic (no pointer arrays ->
// no scratch, rule #20).
// ---------------------------------------------------------------------------
__device__ __align__(16) float          g_Qf[MD_];            // 64 MiB fp32 q
__device__ __align__(16) float          g_Kf[MD_];            // 64 MiB fp32 k
__device__ __align__(16) unsigned short g_Qb[MD_];            // 32 MiB bf16 q
__device__ __align__(16) unsigned short g_Kb[MD_];            // 32 MiB bf16 k
__device__ __align__(16) float          g_Vf[MD_];            // 64 MiB fp32 v
__device__ __align__(16) unsigned short g_AO[MD_];            // 32 MiB bf16 attn-out
__device__ __align__(16) unsigned short g_Xp[3 * MD_];        // 96 MiB bf16 X planes
__device__ __align__(16) unsigned short g_Wqp[3 * DD_];       // 6 MiB Wq planes (T)
__device__ __align__(16) unsigned short g_Wkp[3 * DD_];       // 6 MiB Wk planes (T)
__device__ __align__(16) unsigned short g_WvT[DD_];           // 2 MiB bf16
__device__ __align__(16) unsigned short g_WoT[DD_];           // 2 MiB bf16
__device__ __align__(16) float          g_S[(size_t)B_ * N_ * N_]; // 256 MiB scores
__device__ __align__(16) int            g_cand[(size_t)M_ * CAND];
__device__ __align__(16) int            g_t8i[(size_t)M_ * 8];
__device__ __align__(16) float          g_t8w[(size_t)M_ * 8];

#define g_X0 (g_Xp)
#define g_X1 (g_Xp + MD_)
#define g_X2 (g_Xp + 2 * MD_)
#define g_Wq0T (g_Wqp)
#define g_Wq1T (g_Wqp + DD_)
#define g_Wq2T (g_Wqp + 2 * DD_)
#define g_Wk0T (g_Wkp)
#define g_Wk1T (g_Wkp + DD_)
#define g_Wk2T (g_Wkp + 2 * DD_)

__device__ __forceinline__ float b2f(unsigned short u){
  return __uint_as_float(((unsigned int)u) << 16);
}
__device__ __forceinline__ unsigned short f2b(float f){
  unsigned int b = __float_as_uint(f);
  b += 0x7fffu + ((b >> 16) & 1u);   // RNE
  return (unsigned short)(b >> 16);
}
// 3-term bf16 split: x ~= b2f(h0)+b2f(h1)+b2f(h2), residual ~2^-27 |x|.
__device__ __forceinline__ void split3(float x, unsigned short& h0,
                                       unsigned short& h1, unsigned short& h2){
  h0 = f2b(x);
  float r1 = x - b2f(h0);
  h1 = f2b(r1);
  float r2 = r1 - b2f(h1);
  h2 = f2b(r2);
}

// Async global->LDS, 16 B per lane. LDS dest must be wave-uniform base +
// lane*16.
__device__ __forceinline__ void gl_lds16(const void* g, void* l){
  __builtin_amdgcn_global_load_lds(
      (const __attribute__((address_space(1))) unsigned int*)g,
      (__attribute__((address_space(3))) unsigned int*)l, 16, 0, 0);
}

// ---------------------------------------------------------------------------
// Transpose Wv, Wo (fp32 [k][n] -> bf16 [n][k]) for B^T-layout bf16 GEMM
// ---------------------------------------------------------------------------
__global__ __launch_bounds__(256)
void transpose2(const float* __restrict__ Wv, const float* __restrict__ Wo){
  __shared__ float tile[32][33];
  const float* src = blockIdx.z ? Wo : Wv;
  unsigned short* dst = blockIdx.z ? g_WoT : g_WvT;
  int tx = threadIdx.x, ty = threadIdx.y;
  int n0 = blockIdx.x * 32, k0 = blockIdx.y * 32;
  for (int r = ty; r < 32; r += 8) tile[r][tx] = src[(size_t)(k0 + r) * D_ + n0 + tx];
  __syncthreads();
  for (int r = ty; r < 32; r += 8) dst[(size_t)(n0 + r) * D_ + k0 + tx] = f2b(tile[tx][r]);
}

// ---------------------------------------------------------------------------
// Transpose + 3-way split Wq, Wk (fp32 [k][n] -> 3x bf16 [n][k])
// ---------------------------------------------------------------------------
__global__ __launch_bounds__(256)
void split_wT(const float* __restrict__ Wq, const float* __restrict__ Wk){
  __shared__ float tile[32][33];
  const float* src = blockIdx.z ? Wk : Wq;
  unsigned short* d0 = blockIdx.z ? g_Wk0T : g_Wq0T;
  unsigned short* d1 = blockIdx.z ? g_Wk1T : g_Wq1T;
  unsigned short* d2 = blockIdx.z ? g_Wk2T : g_Wq2T;
  int tx = threadIdx.x, ty = threadIdx.y;
  int n0 = blockIdx.x * 32, k0 = blockIdx.y * 32;
  for (int r = ty; r < 32; r += 8) tile[r][tx] = src[(size_t)(k0 + r) * D_ + n0 + tx];
  __syncthreads();
  for (int r = ty; r < 32; r += 8){
    unsigned short h0, h1, h2;
    split3(tile[tx][r], h0, h1, h2);
    size_t o = (size_t)(n0 + r) * D_ + k0 + tx;
    d0[o] = h0; d1[o] = h1; d2[o] = h2;
  }
}

// ---------------------------------------------------------------------------
// 3-way split of X into bf16 planes (elementwise, float4/thread).
// ---------------------------------------------------------------------------
__global__ __launch_bounds__(256)
void split_x(const float* __restrict__ X){
  size_t i = ((size_t)blockIdx.x * 256 + threadIdx.x) * 4;
  if (i >= MD_) return;
  float4 x = *(const float4*)&X[i];
  ushort4 u0, u1, u2;
  split3(x.x, u0.x, u1.x, u2.x);
  split3(x.y, u0.y, u1.y, u2.y);
  split3(x.z, u0.z, u1.z, u2.z);
  split3(x.w, u0.w, u1.w, u2.w);
  *(ushort4*)&g_X0[i] = u0;
  *(ushort4*)&g_X1[i] = u1;
  *(ushort4*)&g_X2[i] = u2;
}

// ---------------------------------------------------------------------------
// Stage one [128 rows][64 K] bf16 half of a K-tile into LDS, swizzled.
// Bank math: row stride = 128 B = exactly 32 banks, so the bank is determined
// ONLY by the in-row byte. The ds_read pattern (16 lanes, consecutive rows,
// same 16B column) therefore needs row bits 0-2 XOR'd into byte bits 4-6:
//   byte ^= ((row & 7) << 4)     [G4 / m214 fix for D=128 bf16 rows, +89%]
// (Round-5 used ((row&4)<<3): one bit -> only 2 column slots -> 8-way
// conflict, SQ_LDS_BANK_CONFLICT 5e7. This spreads 16 lanes over 8 slots =
// all 32 banks, 2 lanes/bank = free.)
// global_load_lds writes LINEARLY, so the swizzle is realized by INVERSE-
// swizzling the per-lane GLOBAL source column (rule #21); XOR is an
// involution and chunk-aligned (toggles byte bits 4-6 only).
// ---------------------------------------------------------------------------
__device__ __forceinline__ void stage_tile(const unsigned short* __restrict__ Ap,
                                           const unsigned short* __restrict__ Bp,
                                           size_t m0, int n0, int ko, int tid,
                                           unsigned short* As, unsigned short* Bs){
  #pragma unroll
  for (int c = 0; c < 4; c++){
    int d = c * 4096 + tid * 16;                    // linear LDS dest byte
    int rw = d >> 7;                                // row (128-B rows)
    int sc = ((d & 127) ^ ((rw & 7) << 4)) >> 1;    // swizzled source col (elems)
    gl_lds16(&Ap[(m0 + rw) * D_ + ko + sc], &As[d >> 1]);
  }
  #pragma unroll
  for (int c = 0; c < 4; c++){
    int d = c * 4096 + tid * 16;
    int rw = d >> 7;
    int sc = ((d & 127) ^ ((rw & 7) << 4)) >> 1;
    gl_lds16(&Bp[(size_t)(n0 + rw) * D_ + ko + sc], &Bs[d >> 1]);
  }
}

// ---------------------------------------------------------------------------
// Q/K projection as ONE bf16 GEMM over virtual K = 6*1024 (K-extension):
//   C = sum_s Aplane[s] @ Bplane[s]^T,  s-pairs (A,B):
//   (0,2),(1,1),(2,0),(0,1),(1,0),(0,0)  == the 6 split terms, small->large.
// 128x128 tile, BK=64, 96 K-tiles, double-buffered LDS (64 KiB, 2 blk/CU),
// 2-deep counted-vmcnt pipeline (T4): stage t+2 after compute t; wait
// vmcnt(8) so the 8 just-issued loads stay in flight across the barrier.
// Raw s_barrier (NOT __syncthreads -- that drains vmcnt(0), the old ceiling).
// ---------------------------------------------------------------------------
__global__ __launch_bounds__(256, 2)
void qk_kext_gemm(const float* __restrict__ bq, const float* __restrict__ bk){
  int p = blockIdx.x;
  int lin = (p & 7) * 256 + (p >> 3);   // bijective: 2048 = 8 * 256
  int mt = lin >> 4;                    // m-tile, slow (A-slab shared by 16)
  int sub = lin & 15;
  int which = sub >> 3;
  int nt = sub & 7;

  const unsigned short* __restrict__ Wbase = which ? g_Wkp : g_Wqp;
  const float* __restrict__ bias = which ? bk : bq;
  float* __restrict__ outf = which ? g_Kf : g_Qf;
  unsigned short* __restrict__ outb = which ? g_Kb : g_Qb;

  __shared__ unsigned short __align__(16) Ab2[2][128 * 64];   // 2 x 16 KiB
  __shared__ unsigned short __align__(16) Bb2[2][128 * 64];   // 2 x 16 KiB

  int tid = threadIdx.x;
  size_t m0 = (size_t)mt * 128;
  int n0 = nt * 128;
  int l = tid & 63, wid = tid >> 6;
  int wm = (wid >> 1) * 64, wn = (wid & 1) * 64;
  int quad = l >> 4, lr = l & 15;

  floatx4 acc[4][4];
  #pragma unroll
  for (int i = 0; i < 4; i++)
    #pragma unroll
    for (int j = 0; j < 4; j++) acc[i][j] = (floatx4)0.0f;

  // prologue: stage K-tiles 0 and 1 (both segment 0: A=X0, B=plane2)
  stage_tile(g_Xp, Wbase + 2 * DD_, m0, n0, 0,  tid, Ab2[0], Bb2[0]);
  stage_tile(g_Xp, Wbase + 2 * DD_, m0, n0, 64, tid, Ab2[1], Bb2[1]);
  asm volatile("s_waitcnt vmcnt(8)" ::: "memory");   // tile 0 landed; tile 1 in flight
  __builtin_amdgcn_s_barrier();
  __builtin_amdgcn_sched_barrier(0);

  for (int t = 0; t < 96; ++t){
    int cur = t & 1;
    const unsigned short* At = Ab2[cur];
    const unsigned short* Bt = Bb2[cur];
    short8 a[2][4], b[2][4];
    #pragma unroll
    for (int kk = 0; kk < 2; kk++){
      #pragma unroll
      for (int mi = 0; mi < 4; mi++){
        int rw = wm + mi * 16 + lr;
        int byt = rw * 128 + ((kk * 64 + quad * 16) ^ ((rw & 7) << 4));
        a[kk][mi] = *(const short8*)&At[byt >> 1];
      }
      #pragma unroll
      for (int ni = 0; ni < 4; ni++){
        int rw = wn + ni * 16 + lr;
        int byt = rw * 128 + ((kk * 64 + quad * 16) ^ ((rw & 7) << 4));
        b[kk][ni] = *(const short8*)&Bt[byt >> 1];
      }
    }
    #pragma unroll
    for (int kk = 0; kk < 2; kk++)
      #pragma unroll
      for (int mi = 0; mi < 4; mi++)
        #pragma unroll
        for (int ni = 0; ni < 4; ni++)
          acc[mi][ni] = __builtin_amdgcn_mfma_f32_16x16x32_bf16(
              a[kk][mi], b[kk][ni], acc[mi][ni], 0, 0, 0);

    asm volatile("" ::: "memory");       // no ds_read may sink past this point
    __builtin_amdgcn_s_barrier();        // all waves done READING buf[cur]
    // stage K-tile t+2 into the buffer just consumed (clamped dummy at tail:
    // re-stages tile 95 into a dead buffer -- values unused, count correct)
    int tn = (t + 2 < 96) ? (t + 2) : 95;
    int s = tn >> 4;
    int ko = (tn & 15) * 64;
    const unsigned short* Ap = g_Xp   + (size_t)((0x124 >> (2 * s)) & 3) * MD_;
    const unsigned short* Bp = Wbase  + (size_t)((0x46  >> (2 * s)) & 3) * DD_;
    stage_tile(Ap, Bp, m0, n0, ko, tid, Ab2[cur], Bb2[cur]);
    asm volatile("s_waitcnt vmcnt(8)" ::: "memory");   // PREV tile's loads done
    __builtin_amdgcn_s_barrier();
    __builtin_amdgcn_sched_barrier(0);   // no ds_read may hoist above
  }

  // C/D layout (m89-verified): col = lane&15, row = quad*4 + reg
  #pragma unroll
  for (int i = 0; i < 4; i++)
    #pragma unroll
    for (int j = 0; j < 4; j++)
      #pragma unroll
      for (int rg = 0; rg < 4; rg++){
        size_t row = m0 + wm + i * 16 + quad * 4 + rg;
        int col = n0 + wn + j * 16 + lr;
        float val = acc[i][j][rg] + bias[col];
        outf[row * D_ + col] = val;
        outb[row * D_ + col] = f2b(val);
      }
}

// ---------------------------------------------------------------------------
// bf16 MFMA GEMM (m93-style): C = A @ Bt^T + bias, fp32 out.
// sel==0: A=g_X0, Bt=g_WvT, C=g_Vf; sel==1: A=g_AO, Bt=g_WoT, C=Cout.
// (Still 2-phase drain structure: LDS conflicts off critical path, T2 null.)
// ---------------------------------------------------------------------------
__global__ __launch_bounds__(256)
void gemm_bf16(const float* __restrict__ bias, float* __restrict__ Cout, int sel){
  const unsigned short* Asrc = sel ? g_AO : g_X0;
  const unsigned short* Bt = sel ? g_WoT : g_WvT;
  float* C = sel ? Cout : g_Vf;
  __shared__ unsigned short __align__(16) As[128 * 32];
  __shared__ unsigned short __align__(16) Bs[128 * 32];
  int p = blockIdx.x;
  int lin = (p & 7) * 128 + (p >> 3);   // bijective: 1024 = 8 * 128
  int mt = lin >> 3;
  int nt = lin & 7;
  int tid = threadIdx.x;
  size_t m0 = (size_t)mt * 128;
  int n0 = nt * 128;
  int l = tid & 63, wid = tid >> 6;
  int wm = (wid >> 1) * 64, wn = (wid & 1) * 64;
  int quad = l >> 4, lr = l & 15;
  int srow = tid >> 2, scol = (tid & 3) * 8;
  floatx4 acc[4][4];
  #pragma unroll
  for (int i = 0; i < 4; i++)
    #pragma unroll
    for (int j = 0; j < 4; j++) acc[i][j] = (floatx4)0.0f;

  for (int k0 = 0; k0 < D_; k0 += 32){
    #pragma unroll
    for (int it = 0; it < 2; it++){
      int r = srow + it * 64;
      int so = r * 32 + scol;
      gl_lds16(&Asrc[(m0 + r) * D_ + k0 + scol], &As[so]);
      gl_lds16(&Bt[(size_t)(n0 + r) * D_ + k0 + scol], &Bs[so]);
    }
    __syncthreads();
    short8 af[4], bf[4];
    #pragma unroll
    for (int i = 0; i < 4; i++) af[i] = *(short8*)&As[(wm + i * 16 + lr) * 32 + quad * 8];
    #pragma unroll
    for (int j = 0; j < 4; j++) bf[j] = *(short8*)&Bs[(wn + j * 16 + lr) * 32 + quad * 8];
    #pragma unroll
    for (int i = 0; i < 4; i++)
      #pragma unroll
      for (int j = 0; j < 4; j++)
        acc[i][j] = __builtin_amdgcn_mfma_f32_16x16x32_bf16(af[i], bf[j], acc[i][j], 0, 0, 0);
    __syncthreads();
  }
  #pragma unroll
  for (int i = 0; i < 4; i++)
    #pragma unroll
    for (int j = 0; j < 4; j++)
      #pragma unroll
      for (int rg = 0; rg < 4; rg++){
        size_t row = m0 + wm + i * 16 + quad * 4 + rg;
        int col = n0 + wn + j * 16 + lr;
        C[row * D_ + col] = acc[i][j][rg] + bias[col];
      }
}

// ---------------------------------------------------------------------------
// Causal score tiles: S[b][i][j] = (q_i . k_j)/32, fp32, 128x128 tiles.
// ---------------------------------------------------------------------------
__global__ __launch_bounds__(256)
void scores_gemm(){
  int jt = blockIdx.x, it = blockIdx.y, b = blockIdx.z;
  if (jt > it) return;
  __shared__ unsigned short __align__(16) As[128 * 32];
  __shared__ unsigned short __align__(16) Bs[128 * 32];
  int tid = threadIdx.x;
  size_t am0 = (size_t)b * N_ + it * 128;   // Q rows (global)
  size_t bn0 = (size_t)b * N_ + jt * 128;   // K rows (global)
  int l = tid & 63, wid = tid >> 6;
  int wm = (wid >> 1) * 64, wn = (wid & 1) * 64;
  int quad = l >> 4, lr = l & 15;
  int srow = tid >> 2, scol = (tid & 3) * 8;
  floatx4 acc[4][4];
  #pragma unroll
  for (int i = 0; i < 4; i++)
    #pragma unroll
    for (int j = 0; j < 4; j++) acc[i][j] = (floatx4)0.0f;

  for (int k0 = 0; k0 < D_; k0 += 32){
    #pragma unroll
    for (int it2 = 0; it2 < 2; it2++){
      int r = srow + it2 * 64;
      int so = r * 32 + scol;
      gl_lds16(&g_Qb[(am0 + r) * D_ + k0 + scol], &As[so]);
      gl_lds16(&g_Kb[(bn0 + r) * D_ + k0 + scol], &Bs[so]);
    }
    __syncthreads();
    short8 af[4], bf[4];
    #pragma unroll
    for (int i = 0; i < 4; i++) af[i] = *(short8*)&As[(wm + i * 16 + lr) * 32 + quad * 8];
    #pragma unroll
    for (int j = 0; j < 4; j++) bf[j] = *(short8*)&Bs[(wn + j * 16 + lr) * 32 + quad * 8];
    #pragma unroll
    for (int i = 0; i < 4; i++)
      #pragma unroll
      for (int j = 0; j < 4; j++)
        acc[i][j] = __builtin_amdgcn_mfma_f32_16x16x32_bf16(af[i], bf[j], acc[i][j], 0, 0, 0);
    __syncthreads();
  }
  #pragma unroll
  for (int i = 0; i < 4; i++)
    #pragma unroll
    for (int j = 0; j < 4; j++)
      #pragma unroll
      for (int rg = 0; rg < 4; rg++){
        int row = it * 128 + wm + i * 16 + quad * 4 + rg;   // in-batch
        int col = jt * 128 + wn + j * 16 + lr;
        float v = acc[i][j][rg] * 0.03125f;
        if (col > row) v = -3.0e38f;
        g_S[((size_t)b * N_ + row) * N_ + col] = v;
      }
}

// ---------------------------------------------------------------------------
// Per-row top-16 of causal scores. One wave per row (4 rows/block).
// ---------------------------------------------------------------------------
__global__ __launch_bounds__(256)
void row_topk(){
  __shared__ float lv[CAND * 256];   // [u][wave*64+lane]
  __shared__ int   li[CAND * 256];
  int w = threadIdx.x >> 6, l = threadIdx.x & 63;
  int g = threadIdx.x;
  int i = blockIdx.x * 4 + w;               // global row
  int irow = i & (N_ - 1);                  // in-batch row
  const float* Srow = &g_S[(size_t)i * N_];
  #pragma unroll
  for (int u = 0; u < CAND; u++){ lv[u * 256 + g] = -3.0e38f; li[u * 256 + g] = -1; }
  float vmin = -3.0e38f; int pmin = 0;
  for (int j0 = l * 4; j0 <= irow; j0 += 256){
    float4 v4 = *(const float4*)&Srow[j0];
    #pragma unroll
    for (int e = 0; e < 4; e++){
      float v = (&v4.x)[e];
      if (v > vmin){
        lv[pmin * 256 + g] = v; li[pmin * 256 + g] = j0 + e;
        float m = lv[g]; int p = 0;
        #pragma unroll
        for (int u = 1; u < CAND; u++){ float x = lv[u * 256 + g]; if (x < m){ m = x; p = u; } }
        vmin = m; pmin = p;
      }
    }
  }
  float mv = lv[g]; int mp = 0;
  #pragma unroll
  for (int u = 1; u < CAND; u++){ float x = lv[u * 256 + g]; if (x > mv){ mv = x; mp = u; } }
  int mj = li[mp * 256 + g];
  for (int rd = 0; rd < CAND; rd++){
    float bv = mv; int bj = mj; int bl = l;
    #pragma unroll
    for (int off = 32; off >= 1; off >>= 1){
      float ov = __shfl_xor(bv, off);
      int oj = __shfl_xor(bj, off);
      int ol = __shfl_xor(bl, off);
      if (ov > bv || (ov == bv && ol < bl)){ bv = ov; bj = oj; bl = ol; }
    }
    bool valid = (bv > -2.9e38f);
    if (l == 0) g_cand[(size_t)i * CAND + rd] = valid ? bj : -1;
    if (valid && bl == l){
      lv[mp * 256 + g] = -3.0e38f;
      mv = lv[g]; mp = 0;
      #pragma unroll
      for (int u = 1; u < CAND; u++){ float x = lv[u * 256 + g]; if (x > mv){ mv = x; mp = u; } }
      mj = li[mp * 256 + g];
    }
  }
}

// ---------------------------------------------------------------------------
// fp64 rescore of 16 candidates/row -> exact top-8 + softmax weights.
// ---------------------------------------------------------------------------
__global__ __launch_bounds__(256)
void rescore_top8(){
  int i = blockIdx.x;
  int b = i >> 12;
  int tid = threadIdx.x, l = tid & 63, w = tid >> 6;
  __shared__ double cs[CAND];
  __shared__ int cid[CAND];
  if (tid < CAND) cid[tid] = g_cand[(size_t)i * CAND + tid];
  __syncthreads();
  double q[16];
  #pragma unroll
  for (int u = 0; u < 16; u++) q[u] = (double)g_Qf[(size_t)i * D_ + l + 64 * u];
  for (int c = w * 4; c < w * 4 + 4; c++){
    int j = cid[c];
    double s = 0.0;
    if (j >= 0){
      size_t ko = ((size_t)(b * N_ + j)) * D_;
      #pragma unroll
      for (int u = 0; u < 16; u++) s = fma(q[u], (double)g_Kf[ko + l + 64 * u], s);
    }
    #pragma unroll
    for (int off = 32; off >= 1; off >>= 1) s += __shfl_down(s, off);
    if (l == 0) cs[c] = (j >= 0) ? s * 0.03125 : -1.0e300;
  }
  __syncthreads();
  if (tid == 0){
    double v8[8]; int i8[8];
    bool used[CAND];
    for (int u = 0; u < CAND; u++) used[u] = false;
    for (int rk = 0; rk < 8; rk++){
      double best = -1.0e300; int bp = -1;
      for (int c = 0; c < CAND; c++)
        if (!used[c] && cid[c] >= 0 && cs[c] > best){ best = cs[c]; bp = c; }
      if (bp >= 0){ used[bp] = true; v8[rk] = best; i8[rk] = cid[bp]; }
      else { v8[rk] = -1.0e300; i8[rk] = -1; }
    }
    if (i8[0] < 0){ i8[0] = i & (N_ - 1); v8[0] = 0.0; }   // never expected
    double mx = v8[0];
    double e[8]; double Z = 0.0;
    for (int rk = 0; rk < 8; rk++){
      e[rk] = (i8[rk] >= 0) ? exp(v8[rk] - mx) : 0.0;
      Z += e[rk];
    }
    for (int rk = 0; rk < 8; rk++){
      g_t8i[(size_t)i * 8 + rk] = i8[rk];
      g_t8w[(size_t)i * 8 + rk] = (float)(e[rk] / Z);
    }
  }
}

// ---------------------------------------------------------------------------
// attn_out[i] = sum_r w_r * v[idx_r]  (fp32 accumulate, bf16 out for O-GEMM)
// ---------------------------------------------------------------------------
__global__ __launch_bounds__(256)
void gather_v(){
  int i = blockIdx.x;
  int b = i >> 12;
  int tid = threadIdx.x;
  __shared__ float ws8[8];
  __shared__ int id8[8];
  if (tid < 8){ ws8[tid] = g_t8w[(size_t)i * 8 + tid]; id8[tid] = g_t8i[(size_t)i * 8 + tid]; }
  __syncthreads();
  int d0 = tid * 4;
  float a0 = 0.f, a1 = 0.f, a2 = 0.f, a3 = 0.f;
  #pragma unroll
  for (int rk = 0; rk < 8; rk++){
    int j = id8[rk];
    if (j < 0) continue;
    float wgt = ws8[rk];
    float4 vv = *(const float4*)&g_Vf[((size_t)(b * N_ + j)) * D_ + d0];
    a0 += wgt * vv.x; a1 += wgt * vv.y; a2 += wgt * vv.z; a3 += wgt * vv.w;
  }
  ushort4 o;
  o.x = f2b(a0); o.y = f2b(a1); o.z = f2b(a2); o.w = f2b(a3);
  *(ushort4*)&g_AO[(size_t)i * D_ + d0] = o;
}

// ---------------------------------------------------------------------------
extern "C" void kernel_launch(void* const* d_in, const int* in_sizes, int n_in,
                              void* d_out, int out_size, void* d_ws, size_t ws_size,
                              hipStream_t stream){
  const float* S  = (const float*)d_in[0];
  const float* Wq = (const float*)d_in[1];
  const float* bq = (const float*)d_in[2];
  const float* Wk = (const float*)d_in[3];
  const float* bk = (const float*)d_in[4];
  const float* Wv = (const float*)d_in[5];
  const float* bv = (const float*)d_in[6];
  const float* Wo = (const float*)d_in[7];
  const float* bo = (const float*)d_in[8];
  float* out = (float*)d_out;
  (void)d_ws; (void)ws_size; (void)in_sizes; (void)n_in; (void)out_size;

  transpose2<<<dim3(32, 32, 2), dim3(32, 8), 0, stream>>>(Wv, Wo);
  split_wT<<<dim3(32, 32, 2), dim3(32, 8), 0, stream>>>(Wq, Wk);
  split_x<<<dim3(M_), 256, 0, stream>>>(S);   // M_ blocks * 1024 elems = MD_
  qk_kext_gemm<<<dim3(2048), 256, 0, stream>>>(bq, bk);
  gemm_bf16<<<dim3(1024), 256, 0, stream>>>(bv, nullptr, 0);
  scores_gemm<<<dim3(32, 32, 4), 256, 0, stream>>>();
  row_topk<<<dim3(M_ / 4), 256, 0, stream>>>();
  rescore_top8<<<dim3(M_), 256, 0, stream>>>();
  gather_v<<<dim3(M_), 256, 0, stream>>>();
  gemm_bf16<<<dim3(1024), 256, 0, stream>>>(bo, out, 1);
}

// Round 7
// 1121.989 us; speedup vs baseline: 1.2117x; 1.2117x over previous
//
#include <hip/hip_runtime.h>
#include <cstdint>
#include <cstddef>

#define B_ 4
#define N_ 4096
#define D_ 1024
#define CAND 16
#define M_ (B_*N_)
#define MD_ ((size_t)M_ * D_)
#define DD_ ((size_t)D_ * D_)

typedef __attribute__((ext_vector_type(8))) short short8;
typedef __attribute__((ext_vector_type(4))) float floatx4;

// ---------------------------------------------------------------------------
// Static device-global scratch. Every buffer fully overwritten before first
// read on every call.
// Round-7: 2-plane split (hi/lo bf16). 3-term product (X0W0+X0W1+X1W0) gives
// q/k error ~1.2e-5 relative; dropped ~2^-16 terms shift scores by ~5e-6 --
// ordering flips only between scores that close, where softmax weights match
// to the same 5e-6 -> output effect << 0.0078 absmax budget. Halves the qk
// MFMA work vs the 6-term/3-plane version.
// ---------------------------------------------------------------------------
__device__ __align__(16) float          g_Qf[MD_];            // 64 MiB fp32 q
__device__ __align__(16) float          g_Kf[MD_];            // 64 MiB fp32 k
__device__ __align__(16) unsigned short g_Qb[MD_];            // 32 MiB bf16 q
__device__ __align__(16) unsigned short g_Kb[MD_];            // 32 MiB bf16 k
__device__ __align__(16) float          g_Vf[MD_];            // 64 MiB fp32 v
__device__ __align__(16) unsigned short g_AO[MD_];            // 32 MiB bf16 attn-out
__device__ __align__(16) unsigned short g_X0[MD_];            // 32 MiB bf16 X hi
__device__ __align__(16) unsigned short g_X1[MD_];            // 32 MiB bf16 X lo
__device__ __align__(16) unsigned short g_Wq0T[DD_];          // 2 MiB each (T)
__device__ __align__(16) unsigned short g_Wq1T[DD_];
__device__ __align__(16) unsigned short g_Wk0T[DD_];
__device__ __align__(16) unsigned short g_Wk1T[DD_];
__device__ __align__(16) unsigned short g_WvT[DD_];           // 2 MiB bf16
__device__ __align__(16) unsigned short g_WoT[DD_];           // 2 MiB bf16
__device__ __align__(16) float          g_S[(size_t)B_ * N_ * N_]; // 256 MiB scores
__device__ __align__(16) int            g_cand[(size_t)M_ * CAND];
__device__ __align__(16) int            g_t8i[(size_t)M_ * 8];
__device__ __align__(16) float          g_t8w[(size_t)M_ * 8];

__device__ __forceinline__ float b2f(unsigned short u){
  return __uint_as_float(((unsigned int)u) << 16);
}
__device__ __forceinline__ unsigned short f2b(float f){
  unsigned int b = __float_as_uint(f);
  b += 0x7fffu + ((b >> 16) & 1u);   // RNE
  return (unsigned short)(b >> 16);
}
// 2-term bf16 split: x ~= b2f(h0)+b2f(h1), residual ~2^-17 |x|.
__device__ __forceinline__ void split2(float x, unsigned short& h0,
                                       unsigned short& h1){
  h0 = f2b(x);
  float r1 = x - b2f(h0);   // exact (Sterbenz)
  h1 = f2b(r1);
}

// Async global->LDS, 16 B per lane. LDS dest must be wave-uniform base +
// lane*16 (our tid*8-short staging layout satisfies this). Completion is
// guaranteed by the vmcnt(0) drain the compiler emits before s_barrier.
__device__ __forceinline__ void gl_lds16(const void* g, void* l){
  __builtin_amdgcn_global_load_lds(
      (const __attribute__((address_space(1))) unsigned int*)g,
      (__attribute__((address_space(3))) unsigned int*)l, 16, 0, 0);
}

// ---------------------------------------------------------------------------
// Transpose Wv, Wo (fp32 [k][n] -> bf16 [n][k]) for B^T-layout bf16 GEMM
// ---------------------------------------------------------------------------
__global__ __launch_bounds__(256)
void transpose2(const float* __restrict__ Wv, const float* __restrict__ Wo){
  __shared__ float tile[32][33];
  const float* src = blockIdx.z ? Wo : Wv;
  unsigned short* dst = blockIdx.z ? g_WoT : g_WvT;
  int tx = threadIdx.x, ty = threadIdx.y;
  int n0 = blockIdx.x * 32, k0 = blockIdx.y * 32;
  for (int r = ty; r < 32; r += 8) tile[r][tx] = src[(size_t)(k0 + r) * D_ + n0 + tx];
  __syncthreads();
  for (int r = ty; r < 32; r += 8) dst[(size_t)(n0 + r) * D_ + k0 + tx] = f2b(tile[tx][r]);
}

// ---------------------------------------------------------------------------
// Transpose + 2-way split Wq, Wk (fp32 [k][n] -> 2x bf16 [n][k])
// ---------------------------------------------------------------------------
__global__ __launch_bounds__(256)
void split_wT(const float* __restrict__ Wq, const float* __restrict__ Wk){
  __shared__ float tile[32][33];
  const float* src = blockIdx.z ? Wk : Wq;
  unsigned short* d0 = blockIdx.z ? g_Wk0T : g_Wq0T;
  unsigned short* d1 = blockIdx.z ? g_Wk1T : g_Wq1T;
  int tx = threadIdx.x, ty = threadIdx.y;
  int n0 = blockIdx.x * 32, k0 = blockIdx.y * 32;
  for (int r = ty; r < 32; r += 8) tile[r][tx] = src[(size_t)(k0 + r) * D_ + n0 + tx];
  __syncthreads();
  for (int r = ty; r < 32; r += 8){
    unsigned short h0, h1;
    split2(tile[tx][r], h0, h1);
    size_t o = (size_t)(n0 + r) * D_ + k0 + tx;
    d0[o] = h0; d1[o] = h1;
  }
}

// ---------------------------------------------------------------------------
// 2-way split of X into bf16 planes (elementwise, float4/thread).
// Grid: M_ blocks x 256 thr x 4 elem = MD_ elements exactly.
// ---------------------------------------------------------------------------
__global__ __launch_bounds__(256)
void split_x(const float* __restrict__ X){
  size_t i = ((size_t)blockIdx.x * 256 + threadIdx.x) * 4;
  if (i >= MD_) return;
  float4 x = *(const float4*)&X[i];
  ushort4 u0, u1;
  split2(x.x, u0.x, u1.x);
  split2(x.y, u0.y, u1.y);
  split2(x.z, u0.z, u1.z);
  split2(x.w, u0.w, u1.w);
  *(ushort4*)&g_X0[i] = u0;
  *(ushort4*)&g_X1[i] = u1;
}

// ---------------------------------------------------------------------------
// Q/K projection via 3-term split-bf16 MFMA GEMM (error ~1.2e-5 relative):
//   out = X @ W + bias;  acc += X0W1 + X1W0 + X0W0   [3 MFMAs / pair]
// Round-4 drain structure (the 490 us @ 6-term baseline): 128x128 tile, BK=32,
// global_load_lds width-16 staging, __syncthreads drain. LDS = 32 KiB ->
// up to 3 blocks/CU (was 48 KiB / ~2.3).
// blockIdx.z folded into the 1-D transposed linearization (A-slab sharers
// consecutive for L3 reuse).
// ---------------------------------------------------------------------------
__global__ __launch_bounds__(256, 2)
void qk_split_gemm(const float* __restrict__ bq, const float* __restrict__ bk){
  int p = blockIdx.x;
  int lin = (p & 7) * 256 + (p >> 3);   // bijective: 2048 = 8 * 256
  int mt = lin >> 4;                    // m-tile, slow (A-slab shared by 16)
  int sub = lin & 15;
  int which = sub >> 3;
  int nt = sub & 7;

  const unsigned short* __restrict__ B0 = which ? g_Wk0T : g_Wq0T;
  const unsigned short* __restrict__ B1 = which ? g_Wk1T : g_Wq1T;
  const float* __restrict__ bias = which ? bk : bq;
  float* __restrict__ outf = which ? g_Kf : g_Qf;
  unsigned short* __restrict__ outb = which ? g_Kb : g_Qb;

  __shared__ unsigned short __align__(16) As[2][128 * 32];   // 2 x 8 KiB
  __shared__ unsigned short __align__(16) Bs[2][128 * 32];   // 2 x 8 KiB

  int tid = threadIdx.x;
  size_t m0 = (size_t)mt * 128;
  int n0 = nt * 128;
  int l = tid & 63, wid = tid >> 6;
  int wm = (wid >> 1) * 64, wn = (wid & 1) * 64;
  int quad = l >> 4, lr = l & 15;
  int srow = tid >> 2, scol = (tid & 3) * 8;

  floatx4 acc[4][4];
  #pragma unroll
  for (int i = 0; i < 4; i++)
    #pragma unroll
    for (int j = 0; j < 4; j++) acc[i][j] = (floatx4)0.0f;

  for (int k0 = 0; k0 < D_; k0 += 32){
    #pragma unroll
    for (int it2 = 0; it2 < 2; it2++){
      int r = srow + it2 * 64;
      size_t ao = (m0 + r) * D_ + k0 + scol;
      size_t bo = (size_t)(n0 + r) * D_ + k0 + scol;
      int so = r * 32 + scol;
      gl_lds16(&g_X0[ao], &As[0][so]);
      gl_lds16(&g_X1[ao], &As[1][so]);
      gl_lds16(&B0[bo], &Bs[0][so]);
      gl_lds16(&B1[bo], &Bs[1][so]);
    }
    __syncthreads();   // compiler emits vmcnt(0) drain before barrier
    short8 a0[4], a1[4], b0[4], b1[4];
    #pragma unroll
    for (int i = 0; i < 4; i++){
      int ro = (wm + i * 16 + lr) * 32 + quad * 8;
      a0[i] = *(short8*)&As[0][ro];
      a1[i] = *(short8*)&As[1][ro];
    }
    #pragma unroll
    for (int j = 0; j < 4; j++){
      int ro = (wn + j * 16 + lr) * 32 + quad * 8;
      b0[j] = *(short8*)&Bs[0][ro];
      b1[j] = *(short8*)&Bs[1][ro];
    }
    // order-1 (small, ~2^-8) terms first, then the dominant hi*hi
    #pragma unroll
    for (int i = 0; i < 4; i++)
      #pragma unroll
      for (int j = 0; j < 4; j++){
        acc[i][j] = __builtin_amdgcn_mfma_f32_16x16x32_bf16(a0[i], b1[j], acc[i][j], 0, 0, 0);
        acc[i][j] = __builtin_amdgcn_mfma_f32_16x16x32_bf16(a1[i], b0[j], acc[i][j], 0, 0, 0);
        acc[i][j] = __builtin_amdgcn_mfma_f32_16x16x32_bf16(a0[i], b0[j], acc[i][j], 0, 0, 0);
      }
    __syncthreads();
  }
  // C/D layout (m89-verified): col = lane&15, row = quad*4 + reg
  #pragma unroll
  for (int i = 0; i < 4; i++)
    #pragma unroll
    for (int j = 0; j < 4; j++)
      #pragma unroll
      for (int rg = 0; rg < 4; rg++){
        size_t row = m0 + wm + i * 16 + quad * 4 + rg;
        int col = n0 + wn + j * 16 + lr;
        float val = acc[i][j][rg] + bias[col];
        outf[row * D_ + col] = val;
        outb[row * D_ + col] = f2b(val);
      }
}

// ---------------------------------------------------------------------------
// bf16 MFMA GEMM (m93-style): C = A @ Bt^T + bias, fp32 out.
// sel==0: A=g_X0, Bt=g_WvT, C=g_Vf; sel==1: A=g_AO, Bt=g_WoT, C=Cout.
// ---------------------------------------------------------------------------
__global__ __launch_bounds__(256)
void gemm_bf16(const float* __restrict__ bias, float* __restrict__ Cout, int sel){
  const unsigned short* Asrc = sel ? g_AO : g_X0;
  const unsigned short* Bt = sel ? g_WoT : g_WvT;
  float* C = sel ? Cout : g_Vf;
  __shared__ unsigned short __align__(16) As[128 * 32];
  __shared__ unsigned short __align__(16) Bs[128 * 32];
  int p = blockIdx.x;
  int lin = (p & 7) * 128 + (p >> 3);   // bijective: 1024 = 8 * 128
  int mt = lin >> 3;
  int nt = lin & 7;
  int tid = threadIdx.x;
  size_t m0 = (size_t)mt * 128;
  int n0 = nt * 128;
  int l = tid & 63, wid = tid >> 6;
  int wm = (wid >> 1) * 64, wn = (wid & 1) * 64;
  int quad = l >> 4, lr = l & 15;
  int srow = tid >> 2, scol = (tid & 3) * 8;
  floatx4 acc[4][4];
  #pragma unroll
  for (int i = 0; i < 4; i++)
    #pragma unroll
    for (int j = 0; j < 4; j++) acc[i][j] = (floatx4)0.0f;

  for (int k0 = 0; k0 < D_; k0 += 32){
    #pragma unroll
    for (int it = 0; it < 2; it++){
      int r = srow + it * 64;
      int so = r * 32 + scol;
      gl_lds16(&Asrc[(m0 + r) * D_ + k0 + scol], &As[so]);
      gl_lds16(&Bt[(size_t)(n0 + r) * D_ + k0 + scol], &Bs[so]);
    }
    __syncthreads();
    short8 af[4], bf[4];
    #pragma unroll
    for (int i = 0; i < 4; i++) af[i] = *(short8*)&As[(wm + i * 16 + lr) * 32 + quad * 8];
    #pragma unroll
    for (int j = 0; j < 4; j++) bf[j] = *(short8*)&Bs[(wn + j * 16 + lr) * 32 + quad * 8];
    #pragma unroll
    for (int i = 0; i < 4; i++)
      #pragma unroll
      for (int j = 0; j < 4; j++)
        acc[i][j] = __builtin_amdgcn_mfma_f32_16x16x32_bf16(af[i], bf[j], acc[i][j], 0, 0, 0);
    __syncthreads();
  }
  #pragma unroll
  for (int i = 0; i < 4; i++)
    #pragma unroll
    for (int j = 0; j < 4; j++)
      #pragma unroll
      for (int rg = 0; rg < 4; rg++){
        size_t row = m0 + wm + i * 16 + quad * 4 + rg;
        int col = n0 + wn + j * 16 + lr;
        C[row * D_ + col] = acc[i][j][rg] + bias[col];
      }
}

// ---------------------------------------------------------------------------
// Causal score tiles: S[b][i][j] = (q_i . k_j)/32, fp32, 128x128 tiles.
// Grid (32, 32, 4) = (jt, it, b); jt > it exits early. Diagonal masks j > i.
// ---------------------------------------------------------------------------
__global__ __launch_bounds__(256)
void scores_gemm(){
  int jt = blockIdx.x, it = blockIdx.y, b = blockIdx.z;
  if (jt > it) return;
  __shared__ unsigned short __align__(16) As[128 * 32];
  __shared__ unsigned short __align__(16) Bs[128 * 32];
  int tid = threadIdx.x;
  size_t am0 = (size_t)b * N_ + it * 128;   // Q rows (global)
  size_t bn0 = (size_t)b * N_ + jt * 128;   // K rows (global)
  int l = tid & 63, wid = tid >> 6;
  int wm = (wid >> 1) * 64, wn = (wid & 1) * 64;
  int quad = l >> 4, lr = l & 15;
  int srow = tid >> 2, scol = (tid & 3) * 8;
  floatx4 acc[4][4];
  #pragma unroll
  for (int i = 0; i < 4; i++)
    #pragma unroll
    for (int j = 0; j < 4; j++) acc[i][j] = (floatx4)0.0f;

  for (int k0 = 0; k0 < D_; k0 += 32){
    #pragma unroll
    for (int it2 = 0; it2 < 2; it2++){
      int r = srow + it2 * 64;
      int so = r * 32 + scol;
      gl_lds16(&g_Qb[(am0 + r) * D_ + k0 + scol], &As[so]);
      gl_lds16(&g_Kb[(bn0 + r) * D_ + k0 + scol], &Bs[so]);
    }
    __syncthreads();
    short8 af[4], bf[4];
    #pragma unroll
    for (int i = 0; i < 4; i++) af[i] = *(short8*)&As[(wm + i * 16 + lr) * 32 + quad * 8];
    #pragma unroll
    for (int j = 0; j < 4; j++) bf[j] = *(short8*)&Bs[(wn + j * 16 + lr) * 32 + quad * 8];
    #pragma unroll
    for (int i = 0; i < 4; i++)
      #pragma unroll
      for (int j = 0; j < 4; j++)
        acc[i][j] = __builtin_amdgcn_mfma_f32_16x16x32_bf16(af[i], bf[j], acc[i][j], 0, 0, 0);
    __syncthreads();
  }
  #pragma unroll
  for (int i = 0; i < 4; i++)
    #pragma unroll
    for (int j = 0; j < 4; j++)
      #pragma unroll
      for (int rg = 0; rg < 4; rg++){
        int row = it * 128 + wm + i * 16 + quad * 4 + rg;   // in-batch
        int col = jt * 128 + wn + j * 16 + lr;
        float v = acc[i][j][rg] * 0.03125f;
        if (col > row) v = -3.0e38f;
        g_S[((size_t)b * N_ + row) * N_ + col] = v;
      }
}

// ---------------------------------------------------------------------------
// Per-row top-16 of causal scores. One wave per row (4 rows/block).
// ---------------------------------------------------------------------------
__global__ __launch_bounds__(256)
void row_topk(){
  __shared__ float lv[CAND * 256];   // [u][wave*64+lane]
  __shared__ int   li[CAND * 256];
  int w = threadIdx.x >> 6, l = threadIdx.x & 63;
  int g = threadIdx.x;
  int i = blockIdx.x * 4 + w;               // global row
  int irow = i & (N_ - 1);                  // in-batch row
  const float* Srow = &g_S[(size_t)i * N_];
  #pragma unroll
  for (int u = 0; u < CAND; u++){ lv[u * 256 + g] = -3.0e38f; li[u * 256 + g] = -1; }
  float vmin = -3.0e38f; int pmin = 0;
  for (int j0 = l * 4; j0 <= irow; j0 += 256){
    float4 v4 = *(const float4*)&Srow[j0];
    #pragma unroll
    for (int e = 0; e < 4; e++){
      float v = (&v4.x)[e];
      if (v > vmin){
        lv[pmin * 256 + g] = v; li[pmin * 256 + g] = j0 + e;
        float m = lv[g]; int p = 0;
        #pragma unroll
        for (int u = 1; u < CAND; u++){ float x = lv[u * 256 + g]; if (x < m){ m = x; p = u; } }
        vmin = m; pmin = p;
      }
    }
  }
  float mv = lv[g]; int mp = 0;
  #pragma unroll
  for (int u = 1; u < CAND; u++){ float x = lv[u * 256 + g]; if (x > mv){ mv = x; mp = u; } }
  int mj = li[mp * 256 + g];
  for (int rd = 0; rd < CAND; rd++){
    float bv = mv; int bj = mj; int bl = l;
    #pragma unroll
    for (int off = 32; off >= 1; off >>= 1){
      float ov = __shfl_xor(bv, off);
      int oj = __shfl_xor(bj, off);
      int ol = __shfl_xor(bl, off);
      if (ov > bv || (ov == bv && ol < bl)){ bv = ov; bj = oj; bl = ol; }
    }
    bool valid = (bv > -2.9e38f);
    if (l == 0) g_cand[(size_t)i * CAND + rd] = valid ? bj : -1;
    if (valid && bl == l){
      lv[mp * 256 + g] = -3.0e38f;
      mv = lv[g]; mp = 0;
      #pragma unroll
      for (int u = 1; u < CAND; u++){ float x = lv[u * 256 + g]; if (x > mv){ mv = x; mp = u; } }
      mj = li[mp * 256 + g];
    }
  }
}

// ---------------------------------------------------------------------------
// fp64 rescore of 16 candidates/row -> exact top-8 + softmax weights.
// ---------------------------------------------------------------------------
__global__ __launch_bounds__(256)
void rescore_top8(){
  int i = blockIdx.x;
  int b = i >> 12;
  int tid = threadIdx.x, l = tid & 63, w = tid >> 6;
  __shared__ double cs[CAND];
  __shared__ int cid[CAND];
  if (tid < CAND) cid[tid] = g_cand[(size_t)i * CAND + tid];
  __syncthreads();
  double q[16];
  #pragma unroll
  for (int u = 0; u < 16; u++) q[u] = (double)g_Qf[(size_t)i * D_ + l + 64 * u];
  for (int c = w * 4; c < w * 4 + 4; c++){
    int j = cid[c];
    double s = 0.0;
    if (j >= 0){
      size_t ko = ((size_t)(b * N_ + j)) * D_;
      #pragma unroll
      for (int u = 0; u < 16; u++) s = fma(q[u], (double)g_Kf[ko + l + 64 * u], s);
    }
    #pragma unroll
    for (int off = 32; off >= 1; off >>= 1) s += __shfl_down(s, off);
    if (l == 0) cs[c] = (j >= 0) ? s * 0.03125 : -1.0e300;
  }
  __syncthreads();
  if (tid == 0){
    double v8[8]; int i8[8];
    bool used[CAND];
    for (int u = 0; u < CAND; u++) used[u] = false;
    for (int rk = 0; rk < 8; rk++){
      double best = -1.0e300; int bp = -1;
      for (int c = 0; c < CAND; c++)
        if (!used[c] && cid[c] >= 0 && cs[c] > best){ best = cs[c]; bp = c; }
      if (bp >= 0){ used[bp] = true; v8[rk] = best; i8[rk] = cid[bp]; }
      else { v8[rk] = -1.0e300; i8[rk] = -1; }
    }
    if (i8[0] < 0){ i8[0] = i & (N_ - 1); v8[0] = 0.0; }   // never expected
    double mx = v8[0];
    double e[8]; double Z = 0.0;
    for (int rk = 0; rk < 8; rk++){
      e[rk] = (i8[rk] >= 0) ? exp(v8[rk] - mx) : 0.0;
      Z += e[rk];
    }
    for (int rk = 0; rk < 8; rk++){
      g_t8i[(size_t)i * 8 + rk] = i8[rk];
      g_t8w[(size_t)i * 8 + rk] = (float)(e[rk] / Z);
    }
  }
}

// ---------------------------------------------------------------------------
// attn_out[i] = sum_r w_r * v[idx_r]  (fp32 accumulate, bf16 out for O-GEMM)
// ---------------------------------------------------------------------------
__global__ __launch_bounds__(256)
void gather_v(){
  int i = blockIdx.x;
  int b = i >> 12;
  int tid = threadIdx.x;
  __shared__ float ws8[8];
  __shared__ int id8[8];
  if (tid < 8){ ws8[tid] = g_t8w[(size_t)i * 8 + tid]; id8[tid] = g_t8i[(size_t)i * 8 + tid]; }
  __syncthreads();
  int d0 = tid * 4;
  float a0 = 0.f, a1 = 0.f, a2 = 0.f, a3 = 0.f;
  #pragma unroll
  for (int rk = 0; rk < 8; rk++){
    int j = id8[rk];
    if (j < 0) continue;
    float wgt = ws8[rk];
    float4 vv = *(const float4*)&g_Vf[((size_t)(b * N_ + j)) * D_ + d0];
    a0 += wgt * vv.x; a1 += wgt * vv.y; a2 += wgt * vv.z; a3 += wgt * vv.w;
  }
  ushort4 o;
  o.x = f2b(a0); o.y = f2b(a1); o.z = f2b(a2); o.w = f2b(a3);
  *(ushort4*)&g_AO[(size_t)i * D_ + d0] = o;
}

// ---------------------------------------------------------------------------
extern "C" void kernel_launch(void* const* d_in, const int* in_sizes, int n_in,
                              void* d_out, int out_size, void* d_ws, size_t ws_size,
                              hipStream_t stream){
  const float* S  = (const float*)d_in[0];
  const float* Wq = (const float*)d_in[1];
  const float* bq = (const float*)d_in[2];
  const float* Wk = (const float*)d_in[3];
  const float* bk = (const float*)d_in[4];
  const float* Wv = (const float*)d_in[5];
  const float* bv = (const float*)d_in[6];
  const float* Wo = (const float*)d_in[7];
  const float* bo = (const float*)d_in[8];
  float* out = (float*)d_out;
  (void)d_ws; (void)ws_size; (void)in_sizes; (void)n_in; (void)out_size;

  transpose2<<<dim3(32, 32, 2), dim3(32, 8), 0, stream>>>(Wv, Wo);
  split_wT<<<dim3(32, 32, 2), dim3(32, 8), 0, stream>>>(Wq, Wk);
  split_x<<<dim3(M_), 256, 0, stream>>>(S);   // M_ blocks * 1024 elems = MD_
  qk_split_gemm<<<dim3(2048), 256, 0, stream>>>(bq, bk);
  gemm_bf16<<<dim3(1024), 256, 0, stream>>>(bv, nullptr, 0);
  scores_gemm<<<dim3(32, 32, 4), 256, 0, stream>>>();
  row_topk<<<dim3(M_ / 4), 256, 0, stream>>>();
  rescore_top8<<<dim3(M_), 256, 0, stream>>>();
  gather_v<<<dim3(M_), 256, 0, stream>>>();
  gemm_bf16<<<dim3(1024), 256, 0, stream>>>(bo, out, 1);
}